// Round 3
// baseline (3656.891 us; speedup 1.0000x reference)
//
#include <hip/hip_runtime.h>
#include <math.h>

#define T_STEPS 50
#define NT 1024

// workspace layout (float offsets)
#define WS_FC1T 0          // 1600*256 = 409600  : fc1_w transposed [k][j]
#define WS_W2F  409600     // 32*64*36 = 73728   : folded conv2 [ic][oc][36]
#define WS_W1F  483328     // 36*64    = 2304    : folded conv1 [j][oc*2+ic]
#define WS_TOTAL 485632

// LDS layout (float offsets)
#define L_XT    0          // 2048
#define L_SPK1  2048       // 32 planes, stride 228 = 7296
#define L_RED   9344       // 8*1600 = 12800
#define L_IPART 22144      // 1024
#define L_W1F   23168      // 2304
#define L_WOUT  25472      // 2816
#define L_LIST  28288      // 1600 (ints)
#define L_FLAG  29888      // 448
#define L_CNT   30336      // 16 (pad)
#define L_VC1   30352      // 6272 : conv1 membrane, [py*14+px]*32 + oc
#define L_VC2   36624      // 1600
#define L_BN2   38224      // 192 : s2 | sh2 | b2
#define L_FCP   38416      // 768 : alpha | rho | beta_a (sigmoided)
#define L_TOTALF 39184
#define SMEM_BYTES (L_TOTALF * 4)

__global__ void prep_kernel(const float* __restrict__ conv1_w,
                            const float* __restrict__ conv2_w,
                            const float* __restrict__ fc1_w,
                            float* __restrict__ ws) {
  int i = blockIdx.x * blockDim.x + threadIdx.x;
  if (i < 409600) {
    int k = i >> 8, j = i & 255;
    ws[WS_FC1T + i] = fc1_w[j * 1600 + k];
  } else if (i < 409600 + 73728) {
    int i2 = i - 409600;
    int ic = i2 / 2304, r = i2 % 2304, oc = r / 36, jj = r % 36, u = jj / 6, v = jj % 6;
    float s = 0.f;
    for (int dy = 0; dy < 2; ++dy) {
      int ky = u - dy; if (ky < 0 || ky > 4) continue;
      for (int dx = 0; dx < 2; ++dx) {
        int kx = v - dx; if (kx < 0 || kx > 4) continue;
        s += conv2_w[((oc * 32 + ic) * 5 + ky) * 5 + kx];
      }
    }
    ws[WS_W2F + i2] = 0.25f * s;
  } else if (i < WS_TOTAL) {
    int i3 = i - 483328;
    int jj = i3 >> 6, l = i3 & 63, oc = l >> 1, ic = l & 1, u = jj / 6, v = jj % 6;
    float s = 0.f;
    for (int dy = 0; dy < 2; ++dy) {
      int ky = u - dy; if (ky < 0 || ky > 4) continue;
      for (int dx = 0; dx < 2; ++dx) {
        int kx = v - dx; if (kx < 0 || kx > 4) continue;
        s += conv1_w[((oc * 2 + ic) * 5 + ky) * 5 + kx];
      }
    }
    ws[WS_W1F + i3] = 0.25f * s;
  }
}

__global__ __launch_bounds__(NT) void snn_kernel(
    const float* __restrict__ x,
    const float* __restrict__ bn1_gamma, const float* __restrict__ bn1_beta,
    const float* __restrict__ bn1_mean,  const float* __restrict__ bn1_var,
    const float* __restrict__ bn2_gamma, const float* __restrict__ bn2_beta,
    const float* __restrict__ bn2_mean,  const float* __restrict__ bn2_var,
    const float* __restrict__ beta_c1_raw, const float* __restrict__ beta_c2_raw,
    const float* __restrict__ alpha_raw, const float* __restrict__ rho_raw,
    const float* __restrict__ beta_a_p,  const float* __restrict__ fc_out_w,
    const float* __restrict__ beta_out_p,
    const float* __restrict__ ws, float* __restrict__ out)
{
  extern __shared__ float sm[];
  int* listI = (int*)&sm[L_LIST];
  int* cntI  = (int*)&sm[L_CNT];
  const int tid = threadIdx.x, wave = tid >> 6, lane = tid & 63;
  const int b = blockIdx.x;

  // one-time LDS staging + state zero-init
  for (int i = tid; i < 2304; i += NT) sm[L_W1F + i] = ws[WS_W1F + i];
  for (int i = tid; i < 2816; i += NT) sm[L_WOUT + i] = fc_out_w[i];
  for (int i = tid; i < 6272; i += NT) sm[L_VC1 + i] = 0.f;
  for (int i = tid; i < 1600; i += NT) sm[L_VC2 + i] = 0.f;
  for (int i = tid; i < 12800; i += NT) sm[L_RED + i] = 0.f;
  if (tid < 64) {
    float s2 = bn2_gamma[tid] / sqrtf(bn2_var[tid] + 1e-5f);
    sm[L_BN2 + tid]       = s2;
    sm[L_BN2 + 64 + tid]  = bn2_beta[tid] - bn2_mean[tid] * s2;
    sm[L_BN2 + 128 + tid] = 1.f / (1.f + expf(-beta_c2_raw[tid]));
  }
  if (tid < 256) {
    sm[L_FCP + tid]       = 1.f / (1.f + expf(-alpha_raw[tid]));
    sm[L_FCP + 256 + tid] = 1.f / (1.f + expf(-rho_raw[tid]));
    sm[L_FCP + 512 + tid] = beta_a_p[tid];
  }

  // conv1 lane mapping: lane = oc*2 + ic
  const int oc1 = lane >> 1, ic1 = lane & 1;
  const float s1v  = bn1_gamma[oc1] / sqrtf(bn1_var[oc1] + 1e-5f);
  const float sh1v = bn1_beta[oc1] - bn1_mean[oc1] * s1v;
  const float b1v  = 1.f / (1.f + expf(-beta_c1_raw[oc1]));
  const float beta_o = 1.f / (1.f + expf(-beta_out_p[0]));

  // fc LIF state: wave 0, lane l owns neurons l*4..l*4+3
  float vfc[4] = {0.f,0.f,0.f,0.f}, afc[4] = {0.f,0.f,0.f,0.f}, spf[4] = {0.f,0.f,0.f,0.f};
  float v_out = 0.f, o_sum = 0.f;  // wave0, lane<11

  const float* xbase = x + (size_t)b * T_STEPS * 2048;
  const float* w2f  = ws + WS_W2F;
  const float* fc1T = ws + WS_FC1T;

  float2 xpre = ((const float2*)xbase)[tid];   // prefetch t=0

  __syncthreads();

  for (int t = 0; t < T_STEPS; ++t) {
    // ---- phase 1: commit prefetched x_t to LDS ----
    ((float2*)&sm[L_XT])[tid] = xpre;
    __syncthreads();                                     // barrier A
    {
      int tn = (t + 1 < T_STEPS) ? t + 1 : t;
      xpre = ((const float2*)(xbase + tn * 2048))[tid];  // prefetch t+1
    }

    // ---- phase 2: conv1 (folded 6x6, stride2) + BN + LIF; wave = output row ----
    if (wave < 14) {
      const int py = wave;
      float w[36];
      #pragma unroll
      for (int j = 0; j < 36; ++j) w[j] = sm[L_W1F + j * 64 + lane];
      float acc[14];
      #pragma unroll
      for (int p = 0; p < 14; ++p) acc[p] = 0.f;
      const float* xr = &sm[L_XT + ic1 * 1024 + py * 64];
      #pragma unroll
      for (int r = 0; r < 6; ++r) {
        float row[32];
        const float4* rp = (const float4*)&xr[r * 32];
        #pragma unroll
        for (int q = 0; q < 8; ++q) {
          float4 f = rp[q];
          row[4*q] = f.x; row[4*q+1] = f.y; row[4*q+2] = f.z; row[4*q+3] = f.w;
        }
        #pragma unroll
        for (int v = 0; v < 6; ++v) {
          float wv = w[r * 6 + v];
          #pragma unroll
          for (int px = 0; px < 14; ++px) acc[px] += row[2*px + v] * wv;
        }
      }
      #pragma unroll
      for (int px = 0; px < 14; ++px) acc[px] += __shfl_xor(acc[px], 1);
      if (ic1 == 0) {
        float flag = 0.f;
        #pragma unroll
        for (int px = 0; px < 14; ++px) {
          float c = acc[px] * s1v + sh1v;
          const int vidx = L_VC1 + (py * 14 + px) * 32 + oc1;
          float vold = sm[vidx];
          float v = b1v * vold + (1.f - b1v) * c;
          float s = (v > 1.f) ? 1.f : 0.f;
          sm[vidx] = v * (1.f - s);
          sm[L_SPK1 + oc1 * 228 + py * 16 + px] = s;
          flag += s;
        }
        sm[L_FLAG + oc1 * 14 + py] = flag;
      }
    }
    if (tid == 0) *cntI = 0;
    __syncthreads();                                     // barrier B

    // ---- phase 3: conv2 (folded 6x6, stride2), row-gated; lane=oc, wave owns 2 ic ----
    {
      float acc[25];
      #pragma unroll
      for (int p = 0; p < 25; ++p) acc[p] = 0.f;
      #pragma unroll
      for (int ib = 0; ib < 2; ++ib) {
        const int ic = wave + 16 * ib;
        float w[36];
        {
          const float4* wp = (const float4*)(w2f + (ic * 64 + lane) * 36);
          #pragma unroll
          for (int q = 0; q < 9; ++q) {
            float4 f = wp[q];
            w[4*q] = f.x; w[4*q+1] = f.y; w[4*q+2] = f.z; w[4*q+3] = f.w;
          }
        }
        const float* srow = &sm[L_SPK1 + ic * 228];
        const float* fl = &sm[L_FLAG + ic * 14];
        #pragma unroll
        for (int iy = 0; iy < 14; ++iy) {
          if (fl[iy] != 0.f) {           // wave-uniform branch; exact (row all zero)
            float row[16];
            const float4* rp = (const float4*)&srow[iy * 16];
            #pragma unroll
            for (int q = 0; q < 4; ++q) {
              float4 f = rp[q];
              row[4*q] = f.x; row[4*q+1] = f.y; row[4*q+2] = f.z; row[4*q+3] = f.w;
            }
            #pragma unroll
            for (int py = 0; py < 5; ++py) {
              const int u = iy - 2 * py;
              if (u >= 0 && u <= 5) {
                #pragma unroll
                for (int v = 0; v < 6; ++v) {
                  float wv = w[u * 6 + v];
                  #pragma unroll
                  for (int px = 0; px < 5; ++px) acc[py * 5 + px] += row[2*px + v] * wv;
                }
              }
            }
          }
        }
      }
      #pragma unroll
      for (int p = 0; p < 25; ++p)
        atomicAdd(&sm[L_RED + (wave & 7) * 1600 + lane * 25 + p], acc[p]);
    }
    __syncthreads();                                     // barrier C

    // ---- phase 4: reduce + BN + LIF -> spike list (ballot compaction); re-zero RED ----
    {
      #pragma unroll
      for (int k = 0; k < 2; ++k) {
        int n = tid + NT * k;
        float s = 0.f;
        if (n < 1600) {
          float ssum = 0.f;
          #pragma unroll
          for (int wv = 0; wv < 8; ++wv) {
            ssum += sm[L_RED + wv * 1600 + n];
            sm[L_RED + wv * 1600 + n] = 0.f;   // pre-zero for next step's atomics
          }
          int oc = n / 25;
          float c2 = ssum * sm[L_BN2 + oc] + sm[L_BN2 + 64 + oc];
          float b2 = sm[L_BN2 + 128 + oc];
          const int vidx = L_VC2 + n;
          float vold = sm[vidx];
          float v = b2 * vold + (1.f - b2) * c2;
          s = (v > 1.f) ? 1.f : 0.f;
          sm[vidx] = v * (1.f - s);
        }
        unsigned long long mask = __ballot(s > 0.f);
        if (mask) {
          int base = 0;
          if (lane == 0) base = atomicAdd(cntI, __popcll(mask));
          base = __shfl(base, 0);
          if (s > 0.f) {
            int pos = __popcll(mask & ((1ull << lane) - 1ull));
            listI[base + pos] = n;
          }
        }
      }
    }
    __syncthreads();                                     // barrier D

    // ---- phase 5: fc1 = sparse gather of transposed columns (4-way split) ----
    {
      const int j = tid & 255, h = tid >> 8;
      const int nn = *cntI;
      float I = 0.f;
      for (int i = h; i < nn; i += 4) {
        int k = listI[i];
        I += fc1T[k * 256 + j];
      }
      sm[L_IPART + tid] = I;
    }
    __syncthreads();                                     // barrier E

    // ---- phases 6-8 (wave 0 only): fc adaptive LIF, fc_out, output integrator ----
    // No trailing barrier: next step's barrier A orders IPART reuse.
    if (wave == 0) {
      float s[4];
      #pragma unroll
      for (int k = 0; k < 4; ++k) {
        int j = lane * 4 + k;
        float I = sm[L_IPART + j] + sm[L_IPART + 256 + j] +
                  sm[L_IPART + 512 + j] + sm[L_IPART + 768 + j];
        float al = sm[L_FCP + j], rh = sm[L_FCP + 256 + j], ba = sm[L_FCP + 512 + j];
        afc[k] = rh * afc[k] + (1.f - rh) * spf[k];
        float v = al * vfc[k] + (1.f - al) * I;
        float sp = (v > 1.f + ba * afc[k]) ? 1.f : 0.f;
        vfc[k] = v * (1.f - sp);
        spf[k] = sp;
        s[k] = sp;
      }
      float p[11];
      #pragma unroll
      for (int o = 0; o < 11; ++o) {
        p[o] = 0.f;
        #pragma unroll
        for (int k = 0; k < 4; ++k)
          p[o] += s[k] * sm[L_WOUT + o * 256 + lane * 4 + k];
      }
      #pragma unroll
      for (int m = 1; m < 64; m <<= 1)
        #pragma unroll
        for (int o = 0; o < 11; ++o) p[o] += __shfl_xor(p[o], m);
      float Isel = p[0];
      #pragma unroll
      for (int o = 1; o < 11; ++o) Isel = (lane == o) ? p[o] : Isel;
      if (lane < 11) {
        v_out = beta_o * v_out + (1.f - beta_o) * Isel;
        o_sum += v_out;
      }
    }
  }

  if (wave == 0 && lane < 11) out[b * 11 + lane] = o_sum * (1.f / T_STEPS);
}

extern "C" void kernel_launch(void* const* d_in, const int* in_sizes, int n_in,
                              void* d_out, int out_size, void* d_ws, size_t ws_size,
                              hipStream_t stream) {
  const float* x            = (const float*)d_in[0];
  const float* conv1_w      = (const float*)d_in[1];
  const float* bn1_gamma    = (const float*)d_in[2];
  const float* bn1_beta     = (const float*)d_in[3];
  const float* bn1_mean     = (const float*)d_in[4];
  const float* bn1_var      = (const float*)d_in[5];
  const float* conv2_w      = (const float*)d_in[6];
  const float* bn2_gamma    = (const float*)d_in[7];
  const float* bn2_beta     = (const float*)d_in[8];
  const float* bn2_mean     = (const float*)d_in[9];
  const float* bn2_var      = (const float*)d_in[10];
  const float* beta_c1_raw  = (const float*)d_in[11];
  const float* beta_c2_raw  = (const float*)d_in[12];
  const float* fc1_w        = (const float*)d_in[13];
  const float* alpha_raw    = (const float*)d_in[14];
  const float* rho_raw      = (const float*)d_in[15];
  const float* beta_a_p     = (const float*)d_in[16];
  const float* fc_out_w     = (const float*)d_in[17];
  const float* beta_out_p   = (const float*)d_in[18];
  float* ws  = (float*)d_ws;
  float* outp = (float*)d_out;

  (void)in_sizes; (void)n_in; (void)out_size; (void)ws_size;

  hipFuncSetAttribute((const void*)snn_kernel,
                      hipFuncAttributeMaxDynamicSharedMemorySize, SMEM_BYTES);

  prep_kernel<<<dim3((WS_TOTAL + 255) / 256), dim3(256), 0, stream>>>(
      conv1_w, conv2_w, fc1_w, ws);

  snn_kernel<<<dim3(128), dim3(NT), SMEM_BYTES, stream>>>(
      x, bn1_gamma, bn1_beta, bn1_mean, bn1_var,
      bn2_gamma, bn2_beta, bn2_mean, bn2_var,
      beta_c1_raw, beta_c2_raw, alpha_raw, rho_raw, beta_a_p,
      fc_out_w, beta_out_p, ws, outp);
}

// Round 4
// 862.406 us; speedup vs baseline: 4.2403x; 4.2403x over previous
//
#include <hip/hip_runtime.h>
#include <math.h>

#define T_STEPS 50
#define NT 512

// workspace layout (float offsets)
#define WS_FC1T 0          // 1600*256 = 409600  : fc1_w transposed [k][j]
#define WS_W2F  409600     // 32*64*36 = 73728   : folded conv2 [ic][oc][36]
#define WS_W1F  483328     // 36*64    = 2304    : folded conv1 [j][oc*2+ic]
#define WS_TOTAL 485632

// LDS layout (float offsets)
#define L_XT    0          // 2048
#define L_SPK1  2048       // 32 planes, stride 228 = 7296
#define L_RED   9344       // 8*1600 = 12800
#define L_IPART 22144      // 512
#define L_WOUT  22656      // 2816
#define L_LIST  25472      // 1600 (ints)
#define L_FLAG  27072      // 448
#define L_CNT   27520      // 16 (pad)
#define L_VC1   27536      // 6272 : conv1 membrane, [py*14+px]*32 + oc
#define L_VC2   33808      // 1600
#define L_BN2   35408      // 192 : s2 | sh2 | b2
#define L_TOTALF 35600
#define SMEM_BYTES (L_TOTALF * 4)

__global__ void prep_kernel(const float* __restrict__ conv1_w,
                            const float* __restrict__ conv2_w,
                            const float* __restrict__ fc1_w,
                            float* __restrict__ ws) {
  int i = blockIdx.x * blockDim.x + threadIdx.x;
  if (i < 409600) {
    int k = i >> 8, j = i & 255;
    ws[WS_FC1T + i] = fc1_w[j * 1600 + k];
  } else if (i < 409600 + 73728) {
    int i2 = i - 409600;
    int ic = i2 / 2304, r = i2 % 2304, oc = r / 36, jj = r % 36, u = jj / 6, v = jj % 6;
    float s = 0.f;
    for (int dy = 0; dy < 2; ++dy) {
      int ky = u - dy; if (ky < 0 || ky > 4) continue;
      for (int dx = 0; dx < 2; ++dx) {
        int kx = v - dx; if (kx < 0 || kx > 4) continue;
        s += conv2_w[((oc * 32 + ic) * 5 + ky) * 5 + kx];
      }
    }
    ws[WS_W2F + i2] = 0.25f * s;
  } else if (i < WS_TOTAL) {
    int i3 = i - 483328;
    int jj = i3 >> 6, l = i3 & 63, oc = l >> 1, ic = l & 1, u = jj / 6, v = jj % 6;
    float s = 0.f;
    for (int dy = 0; dy < 2; ++dy) {
      int ky = u - dy; if (ky < 0 || ky > 4) continue;
      for (int dx = 0; dx < 2; ++dx) {
        int kx = v - dx; if (kx < 0 || kx > 4) continue;
        s += conv1_w[((oc * 2 + ic) * 5 + ky) * 5 + kx];
      }
    }
    ws[WS_W1F + i3] = 0.25f * s;
  }
}

// block = 512 (8 waves). __launch_bounds__(512,2): 2 waves/EU -> VGPR cap 256;
// conv live-sets (~160) must stay in registers — VGPR caps of 128/64 caused
// 134MB / 1.8GB of HBM spill traffic in earlier rounds.
__global__ __launch_bounds__(NT, 2) void snn_kernel(
    const float* __restrict__ x,
    const float* __restrict__ bn1_gamma, const float* __restrict__ bn1_beta,
    const float* __restrict__ bn1_mean,  const float* __restrict__ bn1_var,
    const float* __restrict__ bn2_gamma, const float* __restrict__ bn2_beta,
    const float* __restrict__ bn2_mean,  const float* __restrict__ bn2_var,
    const float* __restrict__ beta_c1_raw, const float* __restrict__ beta_c2_raw,
    const float* __restrict__ alpha_raw, const float* __restrict__ rho_raw,
    const float* __restrict__ beta_a_p,  const float* __restrict__ fc_out_w,
    const float* __restrict__ beta_out_p,
    const float* __restrict__ ws, float* __restrict__ out)
{
  extern __shared__ float sm[];
  int* listI = (int*)&sm[L_LIST];
  int* cntI  = (int*)&sm[L_CNT];
  const int tid = threadIdx.x, wave = tid >> 6, lane = tid & 63;
  const int b = blockIdx.x;

  // one-time LDS staging + state zero-init
  for (int i = tid; i < 2816; i += NT) sm[L_WOUT + i] = fc_out_w[i];
  for (int i = tid; i < 6272; i += NT) sm[L_VC1 + i] = 0.f;
  for (int i = tid; i < 1600; i += NT) sm[L_VC2 + i] = 0.f;
  if (tid < 64) {
    float s2 = bn2_gamma[tid] / sqrtf(bn2_var[tid] + 1e-5f);
    sm[L_BN2 + tid]       = s2;
    sm[L_BN2 + 64 + tid]  = bn2_beta[tid] - bn2_mean[tid] * s2;
    sm[L_BN2 + 128 + tid] = 1.f / (1.f + expf(-beta_c2_raw[tid]));
  }

  // conv1 lane mapping: lane = oc*2 + ic
  const int oc1 = lane >> 1, ic1 = lane & 1;
  const float s1v  = bn1_gamma[oc1] / sqrtf(bn1_var[oc1] + 1e-5f);
  const float sh1v = bn1_beta[oc1] - bn1_mean[oc1] * s1v;
  const float b1v  = 1.f / (1.f + expf(-beta_c1_raw[oc1]));
  const float beta_o = 1.f / (1.f + expf(-beta_out_p[0]));

  // conv1 weights: persistent in registers (36 regs)
  float w1r[36];
  #pragma unroll
  for (int j = 0; j < 36; ++j) w1r[j] = ws[WS_W1F + j * 64 + lane];

  int pyBase, npy;
  if (wave < 6) { pyBase = wave * 2; npy = 2; } else { pyBase = 12 + (wave - 6); npy = 1; }

  // fc LIF state + params: wave 0, lane l owns neurons l*4..l*4+3 (registers)
  float vfc[4] = {0.f,0.f,0.f,0.f}, afc[4] = {0.f,0.f,0.f,0.f}, spf[4] = {0.f,0.f,0.f,0.f};
  float alr[4], rhr[4], bar[4];
  #pragma unroll
  for (int k = 0; k < 4; ++k) {
    int j = lane * 4 + k;   // valid for wave 0; harmless garbage-free loads for others
    alr[k] = 1.f / (1.f + expf(-alpha_raw[j & 255]));
    rhr[k] = 1.f / (1.f + expf(-rho_raw[j & 255]));
    bar[k] = beta_a_p[j & 255];
  }
  float v_out = 0.f, o_sum = 0.f;  // wave0, lane<11

  const float* xbase = x + (size_t)b * T_STEPS * 2048;
  const float* w2f  = ws + WS_W2F;
  const float* fc1T = ws + WS_FC1T;

  float4 xpre = ((const float4*)xbase)[tid];   // prefetch t=0

  __syncthreads();

  for (int t = 0; t < T_STEPS; ++t) {
    // ---- phase 1: commit prefetched x_t to LDS ----
    ((float4*)&sm[L_XT])[tid] = xpre;
    __syncthreads();                                     // barrier A
    {
      int tn = (t + 1 < T_STEPS) ? t + 1 : t;
      xpre = ((const float4*)(xbase + tn * 2048))[tid];  // prefetch t+1 (latency hidden)
    }

    // ---- phase 2: conv1 (folded 6x6, stride2) + BN + LIF ----
    for (int rr = 0; rr < npy; ++rr) {
      const int py = pyBase + rr;
      float acc[14];
      #pragma unroll
      for (int p = 0; p < 14; ++p) acc[p] = 0.f;
      const float* xr = &sm[L_XT + ic1 * 1024 + py * 64];
      #pragma unroll
      for (int r = 0; r < 6; ++r) {
        float row[32];
        const float4* rp = (const float4*)&xr[r * 32];
        #pragma unroll
        for (int q = 0; q < 8; ++q) {
          float4 f = rp[q];
          row[4*q] = f.x; row[4*q+1] = f.y; row[4*q+2] = f.z; row[4*q+3] = f.w;
        }
        #pragma unroll
        for (int v = 0; v < 6; ++v) {
          float wv = w1r[r * 6 + v];
          #pragma unroll
          for (int px = 0; px < 14; ++px) acc[px] += row[2*px + v] * wv;
        }
      }
      #pragma unroll
      for (int px = 0; px < 14; ++px) acc[px] += __shfl_xor(acc[px], 1);
      if (ic1 == 0) {
        float flag = 0.f;
        #pragma unroll
        for (int px = 0; px < 14; ++px) {
          float c = acc[px] * s1v + sh1v;
          const int vidx = L_VC1 + (py * 14 + px) * 32 + oc1;
          float vold = sm[vidx];
          float v = b1v * vold + (1.f - b1v) * c;
          float s = (v > 1.f) ? 1.f : 0.f;
          sm[vidx] = v * (1.f - s);
          sm[L_SPK1 + oc1 * 228 + py * 16 + px] = s;
          flag += s;
        }
        sm[L_FLAG + oc1 * 14 + py] = flag;
      }
    }
    if (tid == 0) *cntI = 0;
    __syncthreads();                                     // barrier B

    // ---- phase 3: conv2 (folded 6x6, stride2); lane=oc, wave owns 4 ic; plane+row gated ----
    {
      float acc[25];
      #pragma unroll
      for (int p = 0; p < 25; ++p) acc[p] = 0.f;
      for (int ib = 0; ib < 4; ++ib) {
        const int ic = wave + 8 * ib;
        const float* fl = &sm[L_FLAG + ic * 14];
        float flg[14]; float fsum = 0.f;
        #pragma unroll
        for (int iy = 0; iy < 14; ++iy) { flg[iy] = fl[iy]; fsum += flg[iy]; }
        if (fsum != 0.f) {               // skip dead input planes entirely
          float w[36];
          {
            const float4* wp = (const float4*)(w2f + (ic * 64 + lane) * 36);
            #pragma unroll
            for (int q = 0; q < 9; ++q) {
              float4 f = wp[q];
              w[4*q] = f.x; w[4*q+1] = f.y; w[4*q+2] = f.z; w[4*q+3] = f.w;
            }
          }
          const float* srow = &sm[L_SPK1 + ic * 228];
          #pragma unroll
          for (int iy = 0; iy < 14; ++iy) {
            if (flg[iy] != 0.f) {        // wave-uniform branch; exact (row all zero)
              float row[16];
              const float4* rp = (const float4*)&srow[iy * 16];
              #pragma unroll
              for (int q = 0; q < 4; ++q) {
                float4 f = rp[q];
                row[4*q] = f.x; row[4*q+1] = f.y; row[4*q+2] = f.z; row[4*q+3] = f.w;
              }
              #pragma unroll
              for (int py = 0; py < 5; ++py) {
                const int u = iy - 2 * py;
                if (u >= 0 && u <= 5) {
                  #pragma unroll
                  for (int v = 0; v < 6; ++v) {
                    float wv = w[u * 6 + v];
                    #pragma unroll
                    for (int px = 0; px < 5; ++px) acc[py * 5 + px] += row[2*px + v] * wv;
                  }
                }
              }
            }
          }
        }
      }
      #pragma unroll
      for (int p = 0; p < 25; ++p) sm[L_RED + wave * 1600 + lane * 25 + p] = acc[p];
    }
    __syncthreads();                                     // barrier C

    // ---- phase 4: reduce + BN + LIF -> spike list (ballot compaction) ----
    {
      #pragma unroll
      for (int k = 0; k < 4; ++k) {
        int n = tid + NT * k;
        float s = 0.f;
        if (n < 1600) {
          float ssum = 0.f;
          #pragma unroll
          for (int wv = 0; wv < 8; ++wv) ssum += sm[L_RED + wv * 1600 + n];
          int oc = n / 25;
          float c2 = ssum * sm[L_BN2 + oc] + sm[L_BN2 + 64 + oc];
          float b2 = sm[L_BN2 + 128 + oc];
          const int vidx = L_VC2 + n;
          float vold = sm[vidx];
          float v = b2 * vold + (1.f - b2) * c2;
          s = (v > 1.f) ? 1.f : 0.f;
          sm[vidx] = v * (1.f - s);
        }
        unsigned long long mask = __ballot(s > 0.f);
        if (mask) {
          int base = 0;
          if (lane == 0) base = atomicAdd(cntI, __popcll(mask));
          base = __shfl(base, 0);
          if (s > 0.f) {
            int pos = __popcll(mask & ((1ull << lane) - 1ull));
            listI[base + pos] = n;
          }
        }
      }
    }
    __syncthreads();                                     // barrier D

    // ---- phase 5: fc1 = sparse gather of transposed columns (2-way, dual-acc MLP) ----
    {
      const int j = tid & 255, h = tid >> 8;
      const int nn = *cntI;
      float I0 = 0.f, I1 = 0.f;
      int i = h;
      for (; i + 2 < nn; i += 4) {
        int k0 = listI[i], k1 = listI[i + 2];
        I0 += fc1T[k0 * 256 + j];
        I1 += fc1T[k1 * 256 + j];
      }
      for (; i < nn; i += 2) I0 += fc1T[listI[i] * 256 + j];
      sm[L_IPART + tid] = I0 + I1;
    }
    __syncthreads();                                     // barrier E

    // ---- phases 6-8 (wave 0 only): fc adaptive LIF, fc_out, output integrator ----
    // No trailing barrier: next step's barrier A orders IPART/LIST reuse.
    if (wave == 0) {
      float s[4];
      #pragma unroll
      for (int k = 0; k < 4; ++k) {
        int j = lane * 4 + k;
        float I = sm[L_IPART + j] + sm[L_IPART + 256 + j];
        afc[k] = rhr[k] * afc[k] + (1.f - rhr[k]) * spf[k];
        float v = alr[k] * vfc[k] + (1.f - alr[k]) * I;
        float sp = (v > 1.f + bar[k] * afc[k]) ? 1.f : 0.f;
        vfc[k] = v * (1.f - sp);
        spf[k] = sp;
        s[k] = sp;
      }
      float p[11];
      #pragma unroll
      for (int o = 0; o < 11; ++o) {
        p[o] = 0.f;
        #pragma unroll
        for (int k = 0; k < 4; ++k)
          p[o] += s[k] * sm[L_WOUT + o * 256 + lane * 4 + k];
      }
      #pragma unroll
      for (int m = 1; m < 64; m <<= 1)
        #pragma unroll
        for (int o = 0; o < 11; ++o) p[o] += __shfl_xor(p[o], m);
      float Isel = p[0];
      #pragma unroll
      for (int o = 1; o < 11; ++o) Isel = (lane == o) ? p[o] : Isel;
      if (lane < 11) {
        v_out = beta_o * v_out + (1.f - beta_o) * Isel;
        o_sum += v_out;
      }
    }
  }

  if (wave == 0 && lane < 11) out[b * 11 + lane] = o_sum * (1.f / T_STEPS);
}

extern "C" void kernel_launch(void* const* d_in, const int* in_sizes, int n_in,
                              void* d_out, int out_size, void* d_ws, size_t ws_size,
                              hipStream_t stream) {
  const float* x            = (const float*)d_in[0];
  const float* conv1_w      = (const float*)d_in[1];
  const float* bn1_gamma    = (const float*)d_in[2];
  const float* bn1_beta     = (const float*)d_in[3];
  const float* bn1_mean     = (const float*)d_in[4];
  const float* bn1_var      = (const float*)d_in[5];
  const float* conv2_w      = (const float*)d_in[6];
  const float* bn2_gamma    = (const float*)d_in[7];
  const float* bn2_beta     = (const float*)d_in[8];
  const float* bn2_mean     = (const float*)d_in[9];
  const float* bn2_var      = (const float*)d_in[10];
  const float* beta_c1_raw  = (const float*)d_in[11];
  const float* beta_c2_raw  = (const float*)d_in[12];
  const float* fc1_w        = (const float*)d_in[13];
  const float* alpha_raw    = (const float*)d_in[14];
  const float* rho_raw      = (const float*)d_in[15];
  const float* beta_a_p     = (const float*)d_in[16];
  const float* fc_out_w     = (const float*)d_in[17];
  const float* beta_out_p   = (const float*)d_in[18];
  float* ws  = (float*)d_ws;
  float* outp = (float*)d_out;

  (void)in_sizes; (void)n_in; (void)out_size; (void)ws_size;

  hipFuncSetAttribute((const void*)snn_kernel,
                      hipFuncAttributeMaxDynamicSharedMemorySize, SMEM_BYTES);

  prep_kernel<<<dim3((WS_TOTAL + 255) / 256), dim3(256), 0, stream>>>(
      conv1_w, conv2_w, fc1_w, ws);

  snn_kernel<<<dim3(128), dim3(NT), SMEM_BYTES, stream>>>(
      x, bn1_gamma, bn1_beta, bn1_mean, bn1_var,
      bn2_gamma, bn2_beta, bn2_mean, bn2_var,
      beta_c1_raw, beta_c2_raw, alpha_raw, rho_raw, beta_a_p,
      fc_out_w, beta_out_p, ws, outp);
}